// Round 7
// baseline (94.846 us; speedup 1.0000x reference)
//
#include <hip/hip_runtime.h>
#include <hip/hip_bf16.h>

#define IN_SIZE 65536
#define HIDDEN 128
#define D_STEPS 64
#define N_ACT 512
#define NBLK 256
#define P1_DEPTH 8

typedef _Float16 half2_ __attribute__((ext_vector_type(2)));
typedef _Float16 half8_ __attribute__((ext_vector_type(8)));

__device__ __forceinline__ float dot2f(half2_ a, half2_ b, float c) {
#if __has_builtin(__builtin_amdgcn_fdot2)
    return __builtin_amdgcn_fdot2(a, b, c, false);
#else
    return c + (float)a[0] * (float)b[0] + (float)a[1] * (float)b[1];
#endif
}

// Manual grid barrier; counter zeroed per-launch by captured hipMemsetAsync.
__device__ __forceinline__ void gbar(int* cnt) {
    __syncthreads();
    if (threadIdx.x == 0) {
        __hip_atomic_fetch_add(cnt, 1, __ATOMIC_RELEASE, __HIP_MEMORY_SCOPE_AGENT);
        while (__hip_atomic_load(cnt, __ATOMIC_ACQUIRE, __HIP_MEMORY_SCOPE_AGENT) < NBLK)
            __builtin_amdgcn_s_sleep(8);
    }
    __syncthreads();
}

// Phase 1: block b -> ihx rows 2b,2b+1. Depth-8 double-buffered loads: 16 VMEM
//          in flight per wave continuously (R6: unroll-4 drained to ~4-8 ->
//          1.5 TB/s; need ~20 KB/CU in flight under loaded-HBM latency).
// Phase 2: all blocks redundant (keeps hot path register-allocated; R4/R5 cold
//          branch spilled). 2-way h-split: thread pair (t,t^1) = gates (g,g^1)
//          of same cell; each reads HALF of h (8 ds_read_b128), holds half-rows
//          of both, one shfl_xor reassembles -> LDS instrs/step halved.
// Phase 3: blocks 0..63 -> logits from own-LDS h history.
__global__ __launch_bounds__(512, 1) void fused(
    const float* __restrict__ x,
    const float* __restrict__ w_ih,
    const float* __restrict__ w_hh,
    const float* __restrict__ b_ih,
    const float* __restrict__ b_hh,
    const float* __restrict__ w_lin,
    const float* __restrict__ b_lin,
    int* __restrict__ cnt,
    float* __restrict__ ihx_ws,   // 512 floats
    float* __restrict__ out) {
    int t = threadIdx.x;
    int b = blockIdx.x;

    __shared__ float s[8];
    __shared__ half8_ h_v[2][HIDDEN / 8];
    __shared__ float h_all[D_STEPS][HIDDEN];   // 32 KB

    // ---------------- Phase 1: ihx (2 rows/block, pipelined) ----------------
    {
        int q = t >> 8;             // 0/1: which row
        int u = t & 255;
        int row = 2 * b + q;
        const float4* wp = (const float4*)(w_ih + (size_t)row * IN_SIZE);
        const float4* xp = (const float4*)x;
        float acc = 0.f;
        float4 wv[2][P1_DEPTH], xv[2][P1_DEPTH];
#pragma unroll
        for (int j = 0; j < P1_DEPTH; ++j) {
            wv[0][j] = wp[u + j * 256];
            xv[0][j] = xp[u + j * 256];
        }
#pragma unroll
        for (int g = 0; g < 8; ++g) {           // 8 groups x 8 = 64 float4-pairs
            const int cur = g & 1, nxt = cur ^ 1;
            if (g < 7) {
#pragma unroll
                for (int j = 0; j < P1_DEPTH; ++j) {
                    int idx = u + ((g + 1) * P1_DEPTH + j) * 256;
                    wv[nxt][j] = wp[idx];
                    xv[nxt][j] = xp[idx];
                }
            }
#pragma unroll
            for (int j = 0; j < P1_DEPTH; ++j)
                acc += wv[cur][j].x * xv[cur][j].x + wv[cur][j].y * xv[cur][j].y +
                       wv[cur][j].z * xv[cur][j].z + wv[cur][j].w * xv[cur][j].w;
        }
#pragma unroll
        for (int off = 32; off; off >>= 1) acc += __shfl_down(acc, off, 64);
        if ((t & 63) == 0) s[t >> 6] = acc;
        __syncthreads();
        if (t == 0)
            ihx_ws[row] = s[0] + s[1] + s[2] + s[3] + b_ih[row] + b_hh[row];
        if (t == 256)
            ihx_ws[row] = s[4] + s[5] + s[6] + s[7] + b_ih[row] + b_hh[row];
    }

    // ---- w_hh half-rows -> 64 packed-f16 VGPRs (overlaps barrier skew) ----
    int gate = t & 3;               // 0:i 1:f 2:g 3:o
    int cell = t >> 2;              // 0..127
    int l = t & 63;
    int half = t & 1;               // which 64-column half this thread owns
    half2_ wrS[32], wrP[32];        // self row + partner row, my half
    {
        int rowS = gate * HIDDEN + cell;
        int rowP = (gate ^ 1) * HIDDEN + cell;
        const float2* wpS = (const float2*)(w_hh + (size_t)rowS * HIDDEN + half * 64);
        const float2* wpP = (const float2*)(w_hh + (size_t)rowP * HIDDEN + half * 64);
#pragma unroll
        for (int i = 0; i < 32; ++i) {
            float2 vS = wpS[i], vP = wpP[i];
            half2_ a = {(_Float16)vS.x, (_Float16)vS.y};
            half2_ c2 = {(_Float16)vP.x, (_Float16)vP.y};
            wrS[i] = a; wrP[i] = c2;
        }
    }
    gbar(cnt);

    // ---------------- Phase 2: recurrence (all blocks, redundant) -------------
    {
        float ihx = ihx_ws[gate * HIDDEN + cell];
        float c = 0.f;
        if (t < HIDDEN / 8) {
            half8_ z = {(_Float16)0.f, (_Float16)0.f, (_Float16)0.f, (_Float16)0.f,
                        (_Float16)0.f, (_Float16)0.f, (_Float16)0.f, (_Float16)0.f};
            h_v[0][t] = z;
        }
        __syncthreads();

        for (int d = 0; d < D_STEPS; ++d) {
            int rbuf = d & 1, wbuf = rbuf ^ 1;
            const half8_* hb = h_v[rbuf] + half * 8;   // my 64-element half of h
            float aS0 = 0.f, aS1 = 0.f, aP0 = 0.f, aP1 = 0.f;
#pragma unroll
            for (int i = 0; i < 8; ++i) {       // 8 x ds_read_b128 (2-addr bcast)
                union { half8_ v8; half2_ p[4]; } u;
                u.v8 = hb[i];
                aS0 = dot2f(wrS[4 * i + 0], u.p[0], aS0);
                aS1 = dot2f(wrS[4 * i + 1], u.p[1], aS1);
                aS0 = dot2f(wrS[4 * i + 2], u.p[2], aS0);
                aS1 = dot2f(wrS[4 * i + 3], u.p[3], aS1);
                aP0 = dot2f(wrP[4 * i + 0], u.p[0], aP0);
                aP1 = dot2f(wrP[4 * i + 1], u.p[1], aP1);
                aP0 = dot2f(wrP[4 * i + 2], u.p[2], aP0);
                aP1 = dot2f(wrP[4 * i + 3], u.p[3], aP1);
            }
            float pS = aS0 + aS1;                         // my row, my half
            float pP = aP0 + aP1;                         // partner row, my half
            float g = ihx + pS + __shfl_xor(pP, 1, 64);   // partner's pP = my row, other half
            float kmul = (gate == 2) ? 2.f : 1.f;
            float sg = 1.f / (1.f + __expf(-kmul * g));
            float act = (gate == 2) ? (2.f * sg - 1.f) : sg;
            int base = l & ~3;
            float ai = __shfl(act, base + 0, 64);
            float af = __shfl(act, base + 1, 64);
            float at = __shfl(act, base + 2, 64);
            float ao = __shfl(act, base + 3, 64);
            c = af * c + ai * at;
            float h = ao * (2.f / (1.f + __expf(-2.f * c)) - 1.f);
            if ((t & 3) == 0) {
                ((_Float16*)&h_v[wbuf][0])[cell] = (_Float16)h;
                h_all[d][cell] = h;
            }
            __syncthreads();
        }
    }

    // ---------------- Phase 3: logits (blocks 0..63, own-LDS h) ---------------
    if (b < D_STEPS) {
        const float* hs = h_all[b];
        const float4* wl = (const float4*)(w_lin + (size_t)t * HIDDEN);
        float acc = b_lin[t];
#pragma unroll
        for (int k = 0; k < HIDDEN / 4; ++k) {
            float4 w4 = wl[k];
            acc += w4.x * hs[4 * k + 0] + w4.y * hs[4 * k + 1] +
                   w4.z * hs[4 * k + 2] + w4.w * hs[4 * k + 3];
        }
        out[b * N_ACT + t] = acc;
    }
}

extern "C" void kernel_launch(void* const* d_in, const int* in_sizes, int n_in,
                              void* d_out, int out_size, void* d_ws, size_t ws_size,
                              hipStream_t stream) {
    const float* x     = (const float*)d_in[0];
    const float* w_ih  = (const float*)d_in[1];
    const float* w_hh  = (const float*)d_in[2];
    const float* b_ih  = (const float*)d_in[3];
    const float* b_hh  = (const float*)d_in[4];
    const float* w_lin = (const float*)d_in[5];
    const float* b_lin = (const float*)d_in[6];
    float* out = (float*)d_out;

    hipMemsetAsync(d_ws, 0, 128, stream);
    int*   cnt    = (int*)d_ws;
    float* ihx_ws = (float*)d_ws + 32;   // 512 floats

    fused<<<NBLK, 512, 0, stream>>>(x, w_ih, w_hh, b_ih, b_hh, w_lin, b_lin,
                                    cnt, ihx_ws, out);
}

// Round 8
// 80.745 us; speedup vs baseline: 1.1746x; 1.1746x over previous
//
#include <hip/hip_runtime.h>
#include <hip/hip_bf16.h>

#define IN_SIZE 65536
#define HIDDEN 128
#define D_STEPS 64
#define N_ACT 512

typedef _Float16 half2_ __attribute__((ext_vector_type(2)));
typedef _Float16 half8_ __attribute__((ext_vector_type(8)));

__device__ __forceinline__ float dot2f(half2_ a, half2_ b, float c) {
#if __has_builtin(__builtin_amdgcn_fdot2)
    return __builtin_amdgcn_fdot2(a, b, c, false);
#else
    return c + (float)a[0] * (float)b[0] + (float)a[1] * (float)b[1];
#endif
}

// ---------------- Kernel A: ihx partials = split-K of w_ih @ x ----------------
// 2048 blocks x 256 threads = 32 waves/CU -> TLP saturates HBM (R2-proven).
// Deterministic: partials[r*4+c] written by exactly one block.
__global__ __launch_bounds__(256) void k_ihx(const float* __restrict__ w_ih,
                                             const float* __restrict__ x,
                                             float* __restrict__ partials) {
    int bid = blockIdx.x;
    int r = bid >> 2;        // row 0..511
    int c = bid & 3;         // chunk 0..3 (16384 cols each)
    int t = threadIdx.x;
    const float4* wp = (const float4*)(w_ih + (size_t)r * IN_SIZE + c * 16384);
    const float4* xp = (const float4*)(x + c * 16384);
    float acc = 0.f;
#pragma unroll
    for (int i = 0; i < 16; ++i) {
        float4 w4 = wp[t + i * 256];
        float4 x4 = xp[t + i * 256];
        acc += w4.x * x4.x + w4.y * x4.y + w4.z * x4.z + w4.w * x4.w;
    }
#pragma unroll
    for (int off = 32; off; off >>= 1) acc += __shfl_down(acc, off, 64);
    __shared__ float s[4];
    if ((t & 63) == 0) s[t >> 6] = acc;
    __syncthreads();
    if (t == 0) partials[r * 4 + c] = s[0] + s[1] + s[2] + s[3];
}

// ---------- Kernel B: 64 blocks, each runs the FULL recurrence redundantly ----
// (identical wall time to 1 block; no grid barrier, no h_hist round-trip),
// then block b computes logits for step d = b from its own LDS history.
// Rec body = R7's 2-way h-split: thread pair (t, t^1) = gates (g, g^1) of the
// same cell; each reads HALF of h (8 ds_read_b128, broadcast), one shfl_xor
// reassembles the full dot.
__global__ __launch_bounds__(512, 1) void k_rec_logits(
    const float* __restrict__ w_hh,
    const float* __restrict__ b_ih,
    const float* __restrict__ b_hh,
    const float* __restrict__ w_lin,
    const float* __restrict__ b_lin,
    const float* __restrict__ partials,
    float* __restrict__ out) {
    int t = threadIdx.x;
    int b = blockIdx.x;      // 0..63: which step this block's logits cover

    int gate = t & 3;        // 0:i 1:f 2:g 3:o
    int cell = t >> 2;       // 0..127
    int l = t & 63;
    int half = t & 1;        // which 64-column half of h this thread owns

    __shared__ half8_ h_v[2][HIDDEN / 8];
    __shared__ float h_all[D_STEPS][HIDDEN];   // 32 KB

    // ---- w_hh half-rows -> 64 packed-f16 VGPRs ----
    half2_ wrS[32], wrP[32];     // self row + partner row, my half
    {
        int rowS = gate * HIDDEN + cell;
        int rowP = (gate ^ 1) * HIDDEN + cell;
        const float2* wpS = (const float2*)(w_hh + (size_t)rowS * HIDDEN + half * 64);
        const float2* wpP = (const float2*)(w_hh + (size_t)rowP * HIDDEN + half * 64);
#pragma unroll
        for (int i = 0; i < 32; ++i) {
            float2 vS = wpS[i], vP = wpP[i];
            half2_ a = {(_Float16)vS.x, (_Float16)vS.y};
            half2_ c2 = {(_Float16)vP.x, (_Float16)vP.y};
            wrS[i] = a; wrP[i] = c2;
        }
    }
    int rowS = gate * HIDDEN + cell;
    float ihx = partials[rowS * 4 + 0] + partials[rowS * 4 + 1] +
                partials[rowS * 4 + 2] + partials[rowS * 4 + 3] +
                b_ih[rowS] + b_hh[rowS];
    float c = 0.f;
    if (t < HIDDEN / 8) {
        half8_ z = {(_Float16)0.f, (_Float16)0.f, (_Float16)0.f, (_Float16)0.f,
                    (_Float16)0.f, (_Float16)0.f, (_Float16)0.f, (_Float16)0.f};
        h_v[0][t] = z;
    }
    __syncthreads();

    for (int d = 0; d < D_STEPS; ++d) {
        int rbuf = d & 1, wbuf = rbuf ^ 1;
        const half8_* hb = h_v[rbuf] + half * 8;   // my 64-element half of h
        float aS0 = 0.f, aS1 = 0.f, aP0 = 0.f, aP1 = 0.f;
#pragma unroll
        for (int i = 0; i < 8; ++i) {       // 8 x ds_read_b128 (2-addr broadcast)
            union { half8_ v8; half2_ p[4]; } u;
            u.v8 = hb[i];
            aS0 = dot2f(wrS[4 * i + 0], u.p[0], aS0);
            aS1 = dot2f(wrS[4 * i + 1], u.p[1], aS1);
            aS0 = dot2f(wrS[4 * i + 2], u.p[2], aS0);
            aS1 = dot2f(wrS[4 * i + 3], u.p[3], aS1);
            aP0 = dot2f(wrP[4 * i + 0], u.p[0], aP0);
            aP1 = dot2f(wrP[4 * i + 1], u.p[1], aP1);
            aP0 = dot2f(wrP[4 * i + 2], u.p[2], aP0);
            aP1 = dot2f(wrP[4 * i + 3], u.p[3], aP1);
        }
        float pS = aS0 + aS1;                        // my row, my half
        float pP = aP0 + aP1;                        // partner row, my half
        float g = ihx + pS + __shfl_xor(pP, 1, 64);  // + my row, other half
        float kmul = (gate == 2) ? 2.f : 1.f;
        float sg = 1.f / (1.f + __expf(-kmul * g));
        float act = (gate == 2) ? (2.f * sg - 1.f) : sg;
        int base = l & ~3;
        float ai = __shfl(act, base + 0, 64);
        float af = __shfl(act, base + 1, 64);
        float at = __shfl(act, base + 2, 64);
        float ao = __shfl(act, base + 3, 64);
        c = af * c + ai * at;
        float h = ao * (2.f / (1.f + __expf(-2.f * c)) - 1.f);
        if ((t & 3) == 0) {
            ((_Float16*)&h_v[wbuf][0])[cell] = (_Float16)h;
            h_all[d][cell] = h;
        }
        __syncthreads();
    }

    // ---- logits for step d = b from own LDS history ----
    {
        const float* hs = h_all[b];
        const float4* wl = (const float4*)(w_lin + (size_t)t * HIDDEN);
        float acc = b_lin[t];
#pragma unroll
        for (int k = 0; k < HIDDEN / 4; ++k) {
            float4 w4 = wl[k];
            acc += w4.x * hs[4 * k + 0] + w4.y * hs[4 * k + 1] +
                   w4.z * hs[4 * k + 2] + w4.w * hs[4 * k + 3];
        }
        out[b * N_ACT + t] = acc;
    }
}

extern "C" void kernel_launch(void* const* d_in, const int* in_sizes, int n_in,
                              void* d_out, int out_size, void* d_ws, size_t ws_size,
                              hipStream_t stream) {
    const float* x     = (const float*)d_in[0];
    const float* w_ih  = (const float*)d_in[1];
    const float* w_hh  = (const float*)d_in[2];
    const float* b_ih  = (const float*)d_in[3];
    const float* b_hh  = (const float*)d_in[4];
    const float* w_lin = (const float*)d_in[5];
    const float* b_lin = (const float*)d_in[6];
    float* out = (float*)d_out;

    float* partials = (float*)d_ws;      // 2048 floats

    k_ihx<<<2048, 256, 0, stream>>>(w_ih, x, partials);
    k_rec_logits<<<D_STEPS, 512, 0, stream>>>(w_hh, b_ih, b_hh, w_lin, b_lin,
                                              partials, out);
}

// Round 9
// 79.430 us; speedup vs baseline: 1.1941x; 1.0166x over previous
//
#include <hip/hip_runtime.h>
#include <hip/hip_bf16.h>

#define IN_SIZE 65536
#define HIDDEN 128
#define D_STEPS 64
#define N_ACT 512

typedef _Float16 half2_ __attribute__((ext_vector_type(2)));
typedef _Float16 half8_ __attribute__((ext_vector_type(8)));

__device__ __forceinline__ float dot2f(half2_ a, half2_ b, float c) {
#if __has_builtin(__builtin_amdgcn_fdot2)
    return __builtin_amdgcn_fdot2(a, b, c, false);
#else
    return c + (float)a[0] * (float)b[0] + (float)a[1] * (float)b[1];
#endif
}

// ---------------- Kernel A: ihx partials ----------------
// 2048 blocks x 256 threads (32 waves/CU). Block = (row-pair, 8192-col chunk):
// x chunk loaded ONCE into regs and reused for both rows -> 24 VMEM/thread
// (was 32), x L2 traffic halved, 2 independent acc chains.
__global__ __launch_bounds__(256) void k_ihx(const float* __restrict__ w_ih,
                                             const float* __restrict__ x,
                                             float* __restrict__ partials) {
    int bid = blockIdx.x;
    int rp = bid >> 3;       // row pair 0..255
    int ck = bid & 7;        // chunk 0..7 (8192 cols each)
    int t = threadIdx.x;
    int r0 = 2 * rp, r1 = 2 * rp + 1;
    const float4* xp = (const float4*)(x + ck * 8192);
    const float4* w0 = (const float4*)(w_ih + (size_t)r0 * IN_SIZE + ck * 8192);
    const float4* w1 = (const float4*)(w_ih + (size_t)r1 * IN_SIZE + ck * 8192);

    float4 xv[8];
#pragma unroll
    for (int i = 0; i < 8; ++i) xv[i] = xp[t + i * 256];

    float a0 = 0.f, a1 = 0.f;
#pragma unroll
    for (int i = 0; i < 8; ++i) {
        float4 w4 = w0[t + i * 256];
        a0 += w4.x * xv[i].x + w4.y * xv[i].y + w4.z * xv[i].z + w4.w * xv[i].w;
    }
#pragma unroll
    for (int i = 0; i < 8; ++i) {
        float4 w4 = w1[t + i * 256];
        a1 += w4.x * xv[i].x + w4.y * xv[i].y + w4.z * xv[i].z + w4.w * xv[i].w;
    }
#pragma unroll
    for (int off = 32; off; off >>= 1) {
        a0 += __shfl_down(a0, off, 64);
        a1 += __shfl_down(a1, off, 64);
    }
    __shared__ float s[8];
    if ((t & 63) == 0) { s[t >> 6] = a0; s[4 + (t >> 6)] = a1; }
    __syncthreads();
    if (t == 0) {
        partials[r0 * 8 + ck] = s[0] + s[1] + s[2] + s[3];
        partials[r1 * 8 + ck] = s[4] + s[5] + s[6] + s[7];
    }
}

// ---------- Kernel B: 64 blocks, full recurrence redundantly + own logits ----
// R8 body (2-way h-split, proven) minus the h_all history: only own-step h is
// kept (h_keep, 512 B), removing 64 per-step LDS writes and 33 KB LDS.
__global__ __launch_bounds__(512, 1) void k_rec_logits(
    const float* __restrict__ w_hh,
    const float* __restrict__ b_ih,
    const float* __restrict__ b_hh,
    const float* __restrict__ w_lin,
    const float* __restrict__ b_lin,
    const float* __restrict__ partials,
    float* __restrict__ out) {
    int t = threadIdx.x;
    int b = blockIdx.x;      // 0..63: which step this block's logits cover

    int gate = t & 3;        // 0:i 1:f 2:g 3:o
    int cell = t >> 2;       // 0..127
    int l = t & 63;
    int half = t & 1;        // which 64-column half of h this thread owns

    __shared__ half8_ h_v[2][HIDDEN / 8];
    __shared__ float h_keep[HIDDEN];

    // ---- w_hh half-rows -> 64 packed-f16 VGPRs ----
    half2_ wrS[32], wrP[32];     // self row + partner row, my half
    {
        int rowS_ = gate * HIDDEN + cell;
        int rowP_ = (gate ^ 1) * HIDDEN + cell;
        const float2* wpS = (const float2*)(w_hh + (size_t)rowS_ * HIDDEN + half * 64);
        const float2* wpP = (const float2*)(w_hh + (size_t)rowP_ * HIDDEN + half * 64);
#pragma unroll
        for (int i = 0; i < 32; ++i) {
            float2 vS = wpS[i], vP = wpP[i];
            half2_ a = {(_Float16)vS.x, (_Float16)vS.y};
            half2_ c2 = {(_Float16)vP.x, (_Float16)vP.y};
            wrS[i] = a; wrP[i] = c2;
        }
    }
    int rowS = gate * HIDDEN + cell;
    float ihx = b_ih[rowS] + b_hh[rowS];
#pragma unroll
    for (int pc = 0; pc < 8; ++pc) ihx += partials[rowS * 8 + pc];

    float c = 0.f;
    if (t < HIDDEN / 8) {
        half8_ z = {(_Float16)0.f, (_Float16)0.f, (_Float16)0.f, (_Float16)0.f,
                    (_Float16)0.f, (_Float16)0.f, (_Float16)0.f, (_Float16)0.f};
        h_v[0][t] = z;
    }
    __syncthreads();

    for (int d = 0; d < D_STEPS; ++d) {
        int rbuf = d & 1, wbuf = rbuf ^ 1;
        const half8_* hb = h_v[rbuf] + half * 8;   // my 64-element half of h
        float aS0 = 0.f, aS1 = 0.f, aP0 = 0.f, aP1 = 0.f;
#pragma unroll
        for (int i = 0; i < 8; ++i) {       // 8 x ds_read_b128 (2-addr broadcast)
            union { half8_ v8; half2_ p[4]; } u;
            u.v8 = hb[i];
            aS0 = dot2f(wrS[4 * i + 0], u.p[0], aS0);
            aS1 = dot2f(wrS[4 * i + 1], u.p[1], aS1);
            aS0 = dot2f(wrS[4 * i + 2], u.p[2], aS0);
            aS1 = dot2f(wrS[4 * i + 3], u.p[3], aS1);
            aP0 = dot2f(wrP[4 * i + 0], u.p[0], aP0);
            aP1 = dot2f(wrP[4 * i + 1], u.p[1], aP1);
            aP0 = dot2f(wrP[4 * i + 2], u.p[2], aP0);
            aP1 = dot2f(wrP[4 * i + 3], u.p[3], aP1);
        }
        float pS = aS0 + aS1;                        // my row, my half
        float pP = aP0 + aP1;                        // partner row, my half
        float g = ihx + pS + __shfl_xor(pP, 1, 64);  // + my row, other half
        float kmul = (gate == 2) ? 2.f : 1.f;
        float sg = 1.f / (1.f + __expf(-kmul * g));
        float act = (gate == 2) ? (2.f * sg - 1.f) : sg;
        int base = l & ~3;
        float ai = __shfl(act, base + 0, 64);
        float af = __shfl(act, base + 1, 64);
        float at = __shfl(act, base + 2, 64);
        float ao = __shfl(act, base + 3, 64);
        c = af * c + ai * at;
        float h = ao * (2.f / (1.f + __expf(-2.f * c)) - 1.f);
        if ((t & 3) == 0) {
            ((_Float16*)&h_v[wbuf][0])[cell] = (_Float16)h;
            if (d == b) h_keep[cell] = h;
        }
        __syncthreads();
    }

    // ---- logits for step d = b from h_keep ----
    {
        const float4* wl = (const float4*)(w_lin + (size_t)t * HIDDEN);
        float acc = b_lin[t];
#pragma unroll
        for (int k = 0; k < HIDDEN / 4; ++k) {
            float4 w4 = wl[k];
            acc += w4.x * h_keep[4 * k + 0] + w4.y * h_keep[4 * k + 1] +
                   w4.z * h_keep[4 * k + 2] + w4.w * h_keep[4 * k + 3];
        }
        out[b * N_ACT + t] = acc;
    }
}

extern "C" void kernel_launch(void* const* d_in, const int* in_sizes, int n_in,
                              void* d_out, int out_size, void* d_ws, size_t ws_size,
                              hipStream_t stream) {
    const float* x     = (const float*)d_in[0];
    const float* w_ih  = (const float*)d_in[1];
    const float* w_hh  = (const float*)d_in[2];
    const float* b_ih  = (const float*)d_in[3];
    const float* b_hh  = (const float*)d_in[4];
    const float* w_lin = (const float*)d_in[5];
    const float* b_lin = (const float*)d_in[6];
    float* out = (float*)d_out;

    float* partials = (float*)d_ws;      // 4096 floats

    k_ihx<<<2048, 256, 0, stream>>>(w_ih, x, partials);
    k_rec_logits<<<D_STEPS, 512, 0, stream>>>(w_hh, b_ih, b_hh, w_lin, b_lin,
                                              partials, out);
}